// Round 2
// baseline (575.143 us; speedup 1.0000x reference)
//
#include <hip/hip_runtime.h>
#include <hip/hip_bf16.h>

// GIN: 3x [agg = segment_sum(h[src], dst); r = h + agg; h = relu(r@Wa+ba)@Wb+bb]
// then mean over nodes @ Wout + bout -> [1,16]
//
// R2: h stored as bf16 (halves gather traffic, h=6.4MB ~ fits L2 better);
// agg fused into the MLP kernel (no r round-trip, matmul hides gather latency).
// CSR build per call (ws is re-poisoned每 launch).

#define NNODES 50000
#define NEDGES 800000
#define DDIM   64
#define DOUT   16

// fp32 -> bf16 RNE (bit trick)
static __device__ __forceinline__ unsigned f2bf(float f) {
    unsigned u = __float_as_uint(f);
    return (u + 0x7fffu + ((u >> 16) & 1u)) >> 16;
}

// ---------------- CSR build ----------------

__global__ void zero_int_kernel(int* p, int n) {
    int i = blockIdx.x * 256 + threadIdx.x;
    if (i < n) p[i] = 0;
}

__global__ void hist_kernel(const int* __restrict__ dst, int* __restrict__ deg, int n) {
    int i = blockIdx.x * 256 + threadIdx.x;
    if (i < n) atomicAdd(&deg[dst[i]], 1);
}

__global__ __launch_bounds__(256) void scan_chunk_kernel(const int* __restrict__ deg,
                                                         int* __restrict__ incl,
                                                         int* __restrict__ bsums, int n) {
    __shared__ int s[256];
    int i = blockIdx.x * 256 + threadIdx.x;
    int v = (i < n) ? deg[i] : 0;
    s[threadIdx.x] = v;
    __syncthreads();
    for (int off = 1; off < 256; off <<= 1) {
        int add = (threadIdx.x >= off) ? s[threadIdx.x - off] : 0;
        __syncthreads();
        s[threadIdx.x] += add;
        __syncthreads();
    }
    if (i < n) incl[i] = s[threadIdx.x];
    if (threadIdx.x == 255) bsums[blockIdx.x] = s[255];
}

__global__ __launch_bounds__(256) void scan_bsums_kernel(const int* __restrict__ bsums,
                                                         int* __restrict__ boff, int nb) {
    __shared__ int s[256];
    int v = (threadIdx.x < nb) ? bsums[threadIdx.x] : 0;
    s[threadIdx.x] = v;
    __syncthreads();
    for (int off = 1; off < 256; off <<= 1) {
        int add = (threadIdx.x >= off) ? s[threadIdx.x - off] : 0;
        __syncthreads();
        s[threadIdx.x] += add;
        __syncthreads();
    }
    boff[threadIdx.x] = s[threadIdx.x] - v;  // exclusive
}

__global__ void finalize_rowptr_kernel(const int* __restrict__ deg,
                                       const int* __restrict__ incl,
                                       const int* __restrict__ boff,
                                       int* __restrict__ rowptr,
                                       int* __restrict__ fillp, int n) {
    int i = blockIdx.x * 256 + threadIdx.x;
    if (i < n) {
        int excl = incl[i] - deg[i] + boff[i >> 8];
        rowptr[i] = excl;
        fillp[i] = excl;
        if (i == n - 1) rowptr[n] = excl + deg[i];
    }
}

__global__ void fill_kernel(const int* __restrict__ src, const int* __restrict__ dst,
                            int* __restrict__ fillp, int* __restrict__ csr, int n) {
    int i = blockIdx.x * 256 + threadIdx.x;
    if (i < n) {
        int p = atomicAdd(&fillp[dst[i]], 1);
        csr[p] = src[i];
    }
}

// ---------------- features fp32 -> bf16 ----------------

__global__ void cvt_kernel(const float2* __restrict__ in, unsigned* __restrict__ out, int n2) {
    int i = blockIdx.x * 256 + threadIdx.x;
    if (i < n2) {
        float2 v = in[i];
        out[i] = f2bf(v.x) | (f2bf(v.y) << 16);
    }
}

// ---------------- fused agg + MLP ----------------
// h stored as bf16x2 packed in uint (row = 32 uints). Per block: 64 nodes.
// Phase 1: gather-sum (self + in-edges) into LDS sR (fp32).
// Phase 2: relu(sR@Wa+ba) -> sR (reused). Phase 3: sR@Wb+bb -> bf16 out.

__global__ __launch_bounds__(256) void agg_mlp_kernel(
    const unsigned* __restrict__ h32,    // bf16x2 [N, 32]
    const int* __restrict__ rowptr, const int* __restrict__ csr,
    const float* __restrict__ Wa, const float* __restrict__ ba,
    const float* __restrict__ Wb, const float* __restrict__ bb,
    unsigned* __restrict__ out32, int n)
{
    __shared__ float sA[64][64];   // Wa[k][j]
    __shared__ float sB[64][64];   // Wb[k][j]
    __shared__ float sR[64][65];   // gathered tile, then hidden tile (reused)
    __shared__ float sba[64], sbb[64];

    int t = threadIdx.x;
    for (int i = t; i < 1024; i += 256) {
        ((float4*)sA)[i] = ((const float4*)Wa)[i];
        ((float4*)sB)[i] = ((const float4*)Wb)[i];
    }
    if (t < 64) { sba[t] = ba[t]; sbb[t] = bb[t]; }

    int node0 = blockIdx.x * 64;
    int g = t >> 5;        // group 0..7 (32 lanes each)
    int p = t & 31;        // uint (bf16-pair) index within row

    // gather: group g handles rows g*8 .. g*8+7
    for (int i = g * 8; i < g * 8 + 8; i++) {
        int gr = node0 + i;
        float a0 = 0.f, a1 = 0.f;
        if (gr < n) {
            unsigned u = h32[(size_t)gr * 32 + p];
            a0 = __uint_as_float(u << 16);
            a1 = __uint_as_float(u & 0xffff0000u);
            int beg = rowptr[gr], end = rowptr[gr + 1];
            int e = beg;
            for (; e + 1 < end; e += 2) {
                int s0 = csr[e], s1 = csr[e + 1];
                unsigned u0 = h32[(size_t)s0 * 32 + p];
                unsigned u1 = h32[(size_t)s1 * 32 + p];
                a0 += __uint_as_float(u0 << 16);
                a1 += __uint_as_float(u0 & 0xffff0000u);
                a0 += __uint_as_float(u1 << 16);
                a1 += __uint_as_float(u1 & 0xffff0000u);
            }
            if (e < end) {
                unsigned u0 = h32[(size_t)csr[e] * 32 + p];
                a0 += __uint_as_float(u0 << 16);
                a1 += __uint_as_float(u0 & 0xffff0000u);
            }
        }
        sR[i][2 * p]     = a0;
        sR[i][2 * p + 1] = a1;
    }
    __syncthreads();

    int tx = t & 15;            // output-col group: j0 = tx*4
    int ty = t >> 4;            // node-row group:  i0 = ty*4
    int j0 = tx * 4, i0 = ty * 4;

    float acc[4][4];
#pragma unroll
    for (int a = 0; a < 4; a++)
#pragma unroll
        for (int b = 0; b < 4; b++) acc[a][b] = 0.f;

#pragma unroll 8
    for (int k = 0; k < 64; k++) {
        float a0 = sR[i0 + 0][k];
        float a1 = sR[i0 + 1][k];
        float a2 = sR[i0 + 2][k];
        float a3 = sR[i0 + 3][k];
        float4 bv = *(const float4*)&sA[k][j0];
        acc[0][0] += a0 * bv.x; acc[0][1] += a0 * bv.y; acc[0][2] += a0 * bv.z; acc[0][3] += a0 * bv.w;
        acc[1][0] += a1 * bv.x; acc[1][1] += a1 * bv.y; acc[1][2] += a1 * bv.z; acc[1][3] += a1 * bv.w;
        acc[2][0] += a2 * bv.x; acc[2][1] += a2 * bv.y; acc[2][2] += a2 * bv.z; acc[2][3] += a2 * bv.w;
        acc[3][0] += a3 * bv.x; acc[3][1] += a3 * bv.y; acc[3][2] += a3 * bv.z; acc[3][3] += a3 * bv.w;
    }
    __syncthreads();   // all reads of sR done before overwrite

#pragma unroll
    for (int a = 0; a < 4; a++)
#pragma unroll
        for (int b = 0; b < 4; b++)
            sR[i0 + a][j0 + b] = fmaxf(acc[a][b] + sba[j0 + b], 0.f);
    __syncthreads();

#pragma unroll
    for (int a = 0; a < 4; a++)
#pragma unroll
        for (int b = 0; b < 4; b++) acc[a][b] = 0.f;

#pragma unroll 8
    for (int k = 0; k < 64; k++) {
        float a0 = sR[i0 + 0][k];
        float a1 = sR[i0 + 1][k];
        float a2 = sR[i0 + 2][k];
        float a3 = sR[i0 + 3][k];
        float4 bv = *(const float4*)&sB[k][j0];
        acc[0][0] += a0 * bv.x; acc[0][1] += a0 * bv.y; acc[0][2] += a0 * bv.z; acc[0][3] += a0 * bv.w;
        acc[1][0] += a1 * bv.x; acc[1][1] += a1 * bv.y; acc[1][2] += a1 * bv.z; acc[1][3] += a1 * bv.w;
        acc[2][0] += a2 * bv.x; acc[2][1] += a2 * bv.y; acc[2][2] += a2 * bv.z; acc[2][3] += a2 * bv.w;
        acc[3][0] += a3 * bv.x; acc[3][1] += a3 * bv.y; acc[3][2] += a3 * bv.z; acc[3][3] += a3 * bv.w;
    }

#pragma unroll
    for (int a = 0; a < 4; a++) {
        int gr = node0 + i0 + a;
        if (gr < n) {
            unsigned q0 = f2bf(acc[a][0] + sbb[j0 + 0]) | (f2bf(acc[a][1] + sbb[j0 + 1]) << 16);
            unsigned q1 = f2bf(acc[a][2] + sbb[j0 + 2]) | (f2bf(acc[a][3] + sbb[j0 + 3]) << 16);
            ((uint2*)(out32 + (size_t)gr * 32))[tx] = make_uint2(q0, q1);
        }
    }
}

// ---------------- mean pool (2 stages, bf16 input) + final linear ----------------

__global__ __launch_bounds__(256) void colsum_part_kernel(const unsigned* __restrict__ h32,
                                                          float* __restrict__ part, int n) {
    __shared__ float red[8][64];
    int t = threadIdx.x;
    int g = t >> 5, p = t & 31;
    float a0 = 0.f, a1 = 0.f;
    for (int i = blockIdx.x * 8 + g; i < n; i += gridDim.x * 8) {
        unsigned u = h32[(size_t)i * 32 + p];
        a0 += __uint_as_float(u << 16);
        a1 += __uint_as_float(u & 0xffff0000u);
    }
    red[g][2 * p]     = a0;
    red[g][2 * p + 1] = a1;
    __syncthreads();
    if (t < 64) {
        float s = 0.f;
        for (int gg = 0; gg < 8; gg++) s += red[gg][t];
        part[blockIdx.x * 64 + t] = s;
    }
}

__global__ __launch_bounds__(64) void final_kernel(const float* __restrict__ part,
                                                   const float* __restrict__ Wout,
                                                   const float* __restrict__ bout,
                                                   float* __restrict__ out, int nparts) {
    __shared__ float cs[64];
    int t = threadIdx.x;
    float s = 0.f;
    for (int b = 0; b < nparts; b++) s += part[b * 64 + t];
    cs[t] = s * (1.0f / (float)NNODES);
    __syncthreads();
    if (t < DOUT) {
        float o = bout[t];
        for (int d = 0; d < DDIM; d++) o += cs[d] * Wout[d * DOUT + t];
        out[t] = o;
    }
}

// ---------------- launch ----------------

extern "C" void kernel_launch(void* const* d_in, const int* in_sizes, int n_in,
                              void* d_out, int out_size, void* d_ws, size_t ws_size,
                              hipStream_t stream) {
    const float* features = (const float*)d_in[0];
    const int*   src      = (const int*)d_in[1];
    const int*   dst      = (const int*)d_in[2];
    const float* W0a = (const float*)d_in[3];  const float* b0a = (const float*)d_in[4];
    const float* W0b = (const float*)d_in[5];  const float* b0b = (const float*)d_in[6];
    const float* W1a = (const float*)d_in[7];  const float* b1a = (const float*)d_in[8];
    const float* W1b = (const float*)d_in[9];  const float* b1b = (const float*)d_in[10];
    const float* W2a = (const float*)d_in[11]; const float* b2a = (const float*)d_in[12];
    const float* W2b = (const float*)d_in[13]; const float* b2b = (const float*)d_in[14];
    const float* Wout = (const float*)d_in[15]; const float* bout = (const float*)d_in[16];
    float* out = (float*)d_out;

    // workspace layout (16B-aligned segments)
    int* deg    = (int*)d_ws;            // [50048]
    int* incl   = deg + 50048;           // [50048]
    int* rowptr = incl + 50048;          // [50064] (50001 used)
    int* fillp  = rowptr + 50064;        // [50048]
    int* bsums  = fillp + 50048;         // [256]
    int* boff   = bsums + 256;           // [256]
    int* csr    = boff + 256;            // [800000]
    unsigned* hb0 = (unsigned*)(csr + 800000);   // bf16 h ping [50000*32]
    unsigned* hb1 = hb0 + NNODES * 32;           // bf16 h pong
    float* part   = (float*)(hb1 + NNODES * 32); // [128*64]

    const int NB_N = (NNODES + 255) / 256;   // 196
    const int NB_E = (NEDGES + 255) / 256;   // 3125

    // CSR build
    zero_int_kernel<<<NB_N, 256, 0, stream>>>(deg, NNODES);
    hist_kernel<<<NB_E, 256, 0, stream>>>(dst, deg, NEDGES);
    scan_chunk_kernel<<<NB_N, 256, 0, stream>>>(deg, incl, bsums, NNODES);
    scan_bsums_kernel<<<1, 256, 0, stream>>>(bsums, boff, NB_N);
    finalize_rowptr_kernel<<<NB_N, 256, 0, stream>>>(deg, incl, boff, rowptr, fillp, NNODES);
    fill_kernel<<<NB_E, 256, 0, stream>>>(src, dst, fillp, csr, NEDGES);

    // features -> bf16
    cvt_kernel<<<(NNODES * 32 + 255) / 256, 256, 0, stream>>>((const float2*)features, hb0, NNODES * 32);

    const int MLP_BLOCKS = (NNODES + 63) / 64;   // 782

    agg_mlp_kernel<<<MLP_BLOCKS, 256, 0, stream>>>(hb0, rowptr, csr, W0a, b0a, W0b, b0b, hb1, NNODES);
    agg_mlp_kernel<<<MLP_BLOCKS, 256, 0, stream>>>(hb1, rowptr, csr, W1a, b1a, W1b, b1b, hb0, NNODES);
    agg_mlp_kernel<<<MLP_BLOCKS, 256, 0, stream>>>(hb0, rowptr, csr, W2a, b2a, W2b, b2b, hb1, NNODES);

    colsum_part_kernel<<<128, 256, 0, stream>>>(hb1, part, NNODES);
    final_kernel<<<1, 64, 0, stream>>>(part, Wout, bout, out, 128);
}

// Round 3
// 368.553 us; speedup vs baseline: 1.5605x; 1.5605x over previous
//
#include <hip/hip_runtime.h>
#include <hip/hip_bf16.h>

// GIN: 3x [agg = segment_sum(h[src], dst); r = h + agg; h = relu(r@Wa+ba)@Wb+bb]
// then mean over nodes @ Wout + bout -> [1,16]
//
// R3: un-fused (fusion killed occupancy / serialized gather). h kept in bf16
// (6.4 MB, L2-friendly). agg: quarter-wave (16 lanes x uint2) per node,
// edge-unroll 4 -> 16 outstanding 128B row loads per wave (MLW-bound fix).
// MLP: 64-node LDS tile, 4x4 register micro-tile, bf16 in/out.

#define NNODES 50000
#define NEDGES 800000
#define DDIM   64
#define DOUT   16

typedef unsigned int uint;

// fp32 -> bf16 RNE (bit trick)
static __device__ __forceinline__ uint f2bf(float f) {
    uint u = __float_as_uint(f);
    return (u + 0x7fffu + ((u >> 16) & 1u)) >> 16;
}
static __device__ __forceinline__ float bf_lo(uint u) { return __uint_as_float(u << 16); }
static __device__ __forceinline__ float bf_hi(uint u) { return __uint_as_float(u & 0xffff0000u); }

// ---------------- CSR build ----------------

__global__ void zero_int_kernel(int* p, int n) {
    int i = blockIdx.x * 256 + threadIdx.x;
    if (i < n) p[i] = 0;
}

__global__ void hist_kernel(const int* __restrict__ dst, int* __restrict__ deg, int n) {
    int i = blockIdx.x * 256 + threadIdx.x;
    if (i < n) atomicAdd(&deg[dst[i]], 1);
}

__global__ __launch_bounds__(256) void scan_chunk_kernel(const int* __restrict__ deg,
                                                         int* __restrict__ incl,
                                                         int* __restrict__ bsums, int n) {
    __shared__ int s[256];
    int i = blockIdx.x * 256 + threadIdx.x;
    int v = (i < n) ? deg[i] : 0;
    s[threadIdx.x] = v;
    __syncthreads();
    for (int off = 1; off < 256; off <<= 1) {
        int add = (threadIdx.x >= off) ? s[threadIdx.x - off] : 0;
        __syncthreads();
        s[threadIdx.x] += add;
        __syncthreads();
    }
    if (i < n) incl[i] = s[threadIdx.x];
    if (threadIdx.x == 255) bsums[blockIdx.x] = s[255];
}

__global__ __launch_bounds__(256) void scan_bsums_kernel(const int* __restrict__ bsums,
                                                         int* __restrict__ boff, int nb) {
    __shared__ int s[256];
    int v = (threadIdx.x < nb) ? bsums[threadIdx.x] : 0;
    s[threadIdx.x] = v;
    __syncthreads();
    for (int off = 1; off < 256; off <<= 1) {
        int add = (threadIdx.x >= off) ? s[threadIdx.x - off] : 0;
        __syncthreads();
        s[threadIdx.x] += add;
        __syncthreads();
    }
    boff[threadIdx.x] = s[threadIdx.x] - v;  // exclusive
}

__global__ void finalize_rowptr_kernel(const int* __restrict__ deg,
                                       const int* __restrict__ incl,
                                       const int* __restrict__ boff,
                                       int* __restrict__ rowptr,
                                       int* __restrict__ fillp, int n) {
    int i = blockIdx.x * 256 + threadIdx.x;
    if (i < n) {
        int excl = incl[i] - deg[i] + boff[i >> 8];
        rowptr[i] = excl;
        fillp[i] = excl;
        if (i == n - 1) rowptr[n] = excl + deg[i];
    }
}

__global__ void fill_kernel(const int* __restrict__ src, const int* __restrict__ dst,
                            int* __restrict__ fillp, int* __restrict__ csr, int n) {
    int i = blockIdx.x * 256 + threadIdx.x;
    if (i < n) {
        int p = atomicAdd(&fillp[dst[i]], 1);
        csr[p] = src[i];
    }
}

// ---------------- features fp32 -> bf16 ----------------

__global__ void cvt_kernel(const float2* __restrict__ in, uint* __restrict__ out, int n2) {
    int i = blockIdx.x * 256 + threadIdx.x;
    if (i < n2) {
        float2 v = in[i];
        out[i] = f2bf(v.x) | (f2bf(v.y) << 16);
    }
}

// ---------------- aggregation (bf16): r[n] = h[n] + sum_{e in(n)} h[src[e]] ----------------
// quarter-wave per node: 16 lanes, each owns one uint2 (4 dims). Unroll 4.

__global__ __launch_bounds__(256) void agg_kernel(const uint2* __restrict__ h64,
                                                  const int* __restrict__ rowptr,
                                                  const int* __restrict__ csr,
                                                  uint2* __restrict__ r64, int n) {
    int idx = blockIdx.x * 256 + threadIdx.x;
    int node = idx >> 4;
    int p = idx & 15;
    if (node >= n) return;
    uint2 u = h64[(size_t)node * 16 + p];
    float a0 = bf_lo(u.x), a1 = bf_hi(u.x), a2 = bf_lo(u.y), a3 = bf_hi(u.y);
    int e = rowptr[node], end = rowptr[node + 1];
    for (; e + 3 < end; e += 4) {
        int s0 = csr[e], s1 = csr[e + 1], s2 = csr[e + 2], s3 = csr[e + 3];
        uint2 u0 = h64[(size_t)s0 * 16 + p];
        uint2 u1 = h64[(size_t)s1 * 16 + p];
        uint2 u2 = h64[(size_t)s2 * 16 + p];
        uint2 u3 = h64[(size_t)s3 * 16 + p];
        a0 += bf_lo(u0.x); a1 += bf_hi(u0.x); a2 += bf_lo(u0.y); a3 += bf_hi(u0.y);
        a0 += bf_lo(u1.x); a1 += bf_hi(u1.x); a2 += bf_lo(u1.y); a3 += bf_hi(u1.y);
        a0 += bf_lo(u2.x); a1 += bf_hi(u2.x); a2 += bf_lo(u2.y); a3 += bf_hi(u2.y);
        a0 += bf_lo(u3.x); a1 += bf_hi(u3.x); a2 += bf_lo(u3.y); a3 += bf_hi(u3.y);
    }
    for (; e < end; e++) {
        uint2 u0 = h64[(size_t)csr[e] * 16 + p];
        a0 += bf_lo(u0.x); a1 += bf_hi(u0.x); a2 += bf_lo(u0.y); a3 += bf_hi(u0.y);
    }
    r64[(size_t)node * 16 + p] =
        make_uint2(f2bf(a0) | (f2bf(a1) << 16), f2bf(a2) | (f2bf(a3) << 16));
}

// ---------------- MLP: out = relu(r@Wa+ba)@Wb+bb  (bf16 in/out) ----------------

__global__ __launch_bounds__(256) void mlp_kernel(const uint2* __restrict__ r64,
                                                  const float* __restrict__ Wa,
                                                  const float* __restrict__ ba,
                                                  const float* __restrict__ Wb,
                                                  const float* __restrict__ bb,
                                                  uint2* __restrict__ out64, int n) {
    __shared__ float sA[64][64];   // Wa[k][j]
    __shared__ float sB[64][64];   // Wb[k][j]
    __shared__ float sR[64][65];   // input tile, reused as hidden tile
    __shared__ float sba[64], sbb[64];

    int t = threadIdx.x;
    for (int i = t; i < 1024; i += 256) {
        ((float4*)sA)[i] = ((const float4*)Wa)[i];
        ((float4*)sB)[i] = ((const float4*)Wb)[i];
    }
    if (t < 64) { sba[t] = ba[t]; sbb[t] = bb[t]; }

    int node0 = blockIdx.x * 64;
    for (int i = t; i < 1024; i += 256) {
        int row = i >> 4;       // 0..63
        int q   = i & 15;       // uint2 index within row
        int gr = node0 + row;
        uint2 v = make_uint2(0u, 0u);
        if (gr < n) v = r64[(size_t)gr * 16 + q];
        sR[row][4 * q + 0] = bf_lo(v.x);
        sR[row][4 * q + 1] = bf_hi(v.x);
        sR[row][4 * q + 2] = bf_lo(v.y);
        sR[row][4 * q + 3] = bf_hi(v.y);
    }
    __syncthreads();

    int tx = t & 15;            // output-col group: j0 = tx*4
    int ty = t >> 4;            // node-row group:  i0 = ty*4
    int j0 = tx * 4, i0 = ty * 4;

    float acc[4][4];
#pragma unroll
    for (int a = 0; a < 4; a++)
#pragma unroll
        for (int b = 0; b < 4; b++) acc[a][b] = 0.f;

#pragma unroll 8
    for (int k = 0; k < 64; k++) {
        float a0 = sR[i0 + 0][k];
        float a1 = sR[i0 + 1][k];
        float a2 = sR[i0 + 2][k];
        float a3 = sR[i0 + 3][k];
        float4 bv = *(const float4*)&sA[k][j0];
        acc[0][0] += a0 * bv.x; acc[0][1] += a0 * bv.y; acc[0][2] += a0 * bv.z; acc[0][3] += a0 * bv.w;
        acc[1][0] += a1 * bv.x; acc[1][1] += a1 * bv.y; acc[1][2] += a1 * bv.z; acc[1][3] += a1 * bv.w;
        acc[2][0] += a2 * bv.x; acc[2][1] += a2 * bv.y; acc[2][2] += a2 * bv.z; acc[2][3] += a2 * bv.w;
        acc[3][0] += a3 * bv.x; acc[3][1] += a3 * bv.y; acc[3][2] += a3 * bv.z; acc[3][3] += a3 * bv.w;
    }
    __syncthreads();   // all reads of sR done before overwrite

#pragma unroll
    for (int a = 0; a < 4; a++)
#pragma unroll
        for (int b = 0; b < 4; b++)
            sR[i0 + a][j0 + b] = fmaxf(acc[a][b] + sba[j0 + b], 0.f);
    __syncthreads();

#pragma unroll
    for (int a = 0; a < 4; a++)
#pragma unroll
        for (int b = 0; b < 4; b++) acc[a][b] = 0.f;

#pragma unroll 8
    for (int k = 0; k < 64; k++) {
        float a0 = sR[i0 + 0][k];
        float a1 = sR[i0 + 1][k];
        float a2 = sR[i0 + 2][k];
        float a3 = sR[i0 + 3][k];
        float4 bv = *(const float4*)&sB[k][j0];
        acc[0][0] += a0 * bv.x; acc[0][1] += a0 * bv.y; acc[0][2] += a0 * bv.z; acc[0][3] += a0 * bv.w;
        acc[1][0] += a1 * bv.x; acc[1][1] += a1 * bv.y; acc[1][2] += a1 * bv.z; acc[1][3] += a1 * bv.w;
        acc[2][0] += a2 * bv.x; acc[2][1] += a2 * bv.y; acc[2][2] += a2 * bv.z; acc[2][3] += a2 * bv.w;
        acc[3][0] += a3 * bv.x; acc[3][1] += a3 * bv.y; acc[3][2] += a3 * bv.z; acc[3][3] += a3 * bv.w;
    }

#pragma unroll
    for (int a = 0; a < 4; a++) {
        int gr = node0 + i0 + a;
        if (gr < n) {
            uint q0 = f2bf(acc[a][0] + sbb[j0 + 0]) | (f2bf(acc[a][1] + sbb[j0 + 1]) << 16);
            uint q1 = f2bf(acc[a][2] + sbb[j0 + 2]) | (f2bf(acc[a][3] + sbb[j0 + 3]) << 16);
            out64[(size_t)gr * 16 + tx] = make_uint2(q0, q1);
        }
    }
}

// ---------------- mean pool (2 stages, bf16 input) + final linear ----------------

__global__ __launch_bounds__(256) void colsum_part_kernel(const uint* __restrict__ h32,
                                                          float* __restrict__ part, int n) {
    __shared__ float red[8][64];
    int t = threadIdx.x;
    int g = t >> 5, p = t & 31;
    float a0 = 0.f, a1 = 0.f;
    for (int i = blockIdx.x * 8 + g; i < n; i += gridDim.x * 8) {
        uint u = h32[(size_t)i * 32 + p];
        a0 += bf_lo(u);
        a1 += bf_hi(u);
    }
    red[g][2 * p]     = a0;
    red[g][2 * p + 1] = a1;
    __syncthreads();
    if (t < 64) {
        float s = 0.f;
        for (int gg = 0; gg < 8; gg++) s += red[gg][t];
        part[blockIdx.x * 64 + t] = s;
    }
}

__global__ __launch_bounds__(64) void final_kernel(const float* __restrict__ part,
                                                   const float* __restrict__ Wout,
                                                   const float* __restrict__ bout,
                                                   float* __restrict__ out, int nparts) {
    __shared__ float cs[64];
    int t = threadIdx.x;
    float s = 0.f;
    for (int b = 0; b < nparts; b++) s += part[b * 64 + t];
    cs[t] = s * (1.0f / (float)NNODES);
    __syncthreads();
    if (t < DOUT) {
        float o = bout[t];
        for (int d = 0; d < DDIM; d++) o += cs[d] * Wout[d * DOUT + t];
        out[t] = o;
    }
}

// ---------------- launch ----------------

extern "C" void kernel_launch(void* const* d_in, const int* in_sizes, int n_in,
                              void* d_out, int out_size, void* d_ws, size_t ws_size,
                              hipStream_t stream) {
    const float* features = (const float*)d_in[0];
    const int*   src      = (const int*)d_in[1];
    const int*   dst      = (const int*)d_in[2];
    const float* W0a = (const float*)d_in[3];  const float* b0a = (const float*)d_in[4];
    const float* W0b = (const float*)d_in[5];  const float* b0b = (const float*)d_in[6];
    const float* W1a = (const float*)d_in[7];  const float* b1a = (const float*)d_in[8];
    const float* W1b = (const float*)d_in[9];  const float* b1b = (const float*)d_in[10];
    const float* W2a = (const float*)d_in[11]; const float* b2a = (const float*)d_in[12];
    const float* W2b = (const float*)d_in[13]; const float* b2b = (const float*)d_in[14];
    const float* Wout = (const float*)d_in[15]; const float* bout = (const float*)d_in[16];
    float* out = (float*)d_out;

    // workspace layout (16B-aligned segments; counts are multiples of 16 ints)
    int* deg    = (int*)d_ws;            // [50048]
    int* incl   = deg + 50048;           // [50048]
    int* rowptr = incl + 50048;          // [50064] (50001 used)
    int* fillp  = rowptr + 50064;        // [50048]
    int* bsums  = fillp + 50048;         // [256]
    int* boff   = bsums + 256;           // [256]
    int* csr    = boff + 256;            // [800000]
    uint* hb0   = (uint*)(csr + 800000); // bf16 h ping [50000*32]
    uint* hb1   = hb0 + NNODES * 32;     // bf16 h pong
    uint* rb    = hb1 + NNODES * 32;     // bf16 r buffer
    float* part = (float*)(rb + NNODES * 32); // [128*64]

    const int NB_N = (NNODES + 255) / 256;   // 196
    const int NB_E = (NEDGES + 255) / 256;   // 3125

    // CSR build
    zero_int_kernel<<<NB_N, 256, 0, stream>>>(deg, NNODES);
    hist_kernel<<<NB_E, 256, 0, stream>>>(dst, deg, NEDGES);
    scan_chunk_kernel<<<NB_N, 256, 0, stream>>>(deg, incl, bsums, NNODES);
    scan_bsums_kernel<<<1, 256, 0, stream>>>(bsums, boff, NB_N);
    finalize_rowptr_kernel<<<NB_N, 256, 0, stream>>>(deg, incl, boff, rowptr, fillp, NNODES);
    fill_kernel<<<NB_E, 256, 0, stream>>>(src, dst, fillp, csr, NEDGES);

    // features -> bf16
    cvt_kernel<<<(NNODES * 32 + 255) / 256, 256, 0, stream>>>((const float2*)features, hb0, NNODES * 32);

    const int AGG_BLOCKS = (NNODES * 16 + 255) / 256;  // 3125 (16 lanes/node)
    const int MLP_BLOCKS = (NNODES + 63) / 64;         // 782

    // layer 0
    agg_kernel<<<AGG_BLOCKS, 256, 0, stream>>>((const uint2*)hb0, rowptr, csr, (uint2*)rb, NNODES);
    mlp_kernel<<<MLP_BLOCKS, 256, 0, stream>>>((const uint2*)rb, W0a, b0a, W0b, b0b, (uint2*)hb1, NNODES);
    // layer 1
    agg_kernel<<<AGG_BLOCKS, 256, 0, stream>>>((const uint2*)hb1, rowptr, csr, (uint2*)rb, NNODES);
    mlp_kernel<<<MLP_BLOCKS, 256, 0, stream>>>((const uint2*)rb, W1a, b1a, W1b, b1b, (uint2*)hb0, NNODES);
    // layer 2
    agg_kernel<<<AGG_BLOCKS, 256, 0, stream>>>((const uint2*)hb0, rowptr, csr, (uint2*)rb, NNODES);
    mlp_kernel<<<MLP_BLOCKS, 256, 0, stream>>>((const uint2*)rb, W2a, b2a, W2b, b2b, (uint2*)hb1, NNODES);

    // mean pool + final linear
    colsum_part_kernel<<<128, 256, 0, stream>>>(hb1, part, NNODES);
    final_kernel<<<1, 64, 0, stream>>>(part, Wout, bout, out, 128);
}